// Round 6
// baseline (172.320 us; speedup 1.0000x reference)
//
#include <hip/hip_runtime.h>
#include <math.h>

#define N_NODES 20000
#define N_EDGES 640000
#define NMAX 8
#define NUM_BASIS 928
#define CH 64             // edge chunk per node-kernel iteration
#define ROW 26            // LDS row stride (dwords): 24 payload + pad, 8B-aligned
#define CAP 80            // bucket capacity (Poisson(32); P(deg>80) ~ 1e-12)
#define SCAN_B 1024
#define SCAN_NB ((N_NODES + SCAN_B - 1) / SCAN_B)   // 20

// ================= primary path: single-pass bucket build =================
__global__ __launch_bounds__(256) void bucket_kernel(
    const float* __restrict__ vectors,
    const int* __restrict__ senders,
    const int* __restrict__ receivers,
    const int* __restrict__ species,
    float4* __restrict__ feat,       // [N_NODES][CAP]
    int* __restrict__ counts)
{
    int e = blockIdx.x * blockDim.x + threadIdx.x;
    if (e >= N_EDGES) return;
    int rcv = receivers[e];
    // atomic first: its latency overlaps the record loads below
    int pos = atomicAdd(&counts[rcv], 1);
    float4 rec;
    rec.x = vectors[3*e+0];
    rec.y = vectors[3*e+1];
    rec.z = vectors[3*e+2];
    rec.w = __int_as_float(species[senders[e]]);
    if (pos < CAP) feat[(size_t)rcv * CAP + pos] = rec;
}

// ================= fallback path: exact CSR of records =================
__global__ __launch_bounds__(256) void count_kernel(const int* __restrict__ receivers,
                                                    int* __restrict__ counts) {
    int e = blockIdx.x * blockDim.x + threadIdx.x;
    if (e < N_EDGES) atomicAdd(&counts[receivers[e]], 1);
}

__global__ __launch_bounds__(SCAN_B) void scan_blocks(const int* __restrict__ counts,
                                                      int* __restrict__ prefix,
                                                      int* __restrict__ blockSums) {
    int tid = threadIdx.x;
    int gid = blockIdx.x * SCAN_B + tid;
    int c = (gid < N_NODES) ? counts[gid] : 0;
    int lane = tid & 63, wave = tid >> 6;
    int s = c;
    #pragma unroll
    for (int off = 1; off < 64; off <<= 1) {
        int v = __shfl_up(s, off);
        if (lane >= off) s += v;
    }
    __shared__ int waveTot[16];
    __shared__ int waveExcl[16];
    if (lane == 63) waveTot[wave] = s;
    __syncthreads();
    if (tid == 0) {
        int run = 0;
        #pragma unroll
        for (int w = 0; w < 16; ++w) { waveExcl[w] = run; run += waveTot[w]; }
        blockSums[blockIdx.x] = run;
    }
    __syncthreads();
    int excl = (s - c) + waveExcl[wave];
    if (gid < N_NODES) prefix[gid] = excl;
}

__global__ __launch_bounds__(SCAN_B) void scan_finalize(const int* __restrict__ prefix,
                                                        const int* __restrict__ blockSums,
                                                        int* __restrict__ offsets,
                                                        int* __restrict__ cursors) {
    __shared__ int blockOff;
    int tid = threadIdx.x;
    if (tid == 0) {
        int run = 0;
        for (int b = 0; b < blockIdx.x; ++b) run += blockSums[b];
        blockOff = run;
    }
    __syncthreads();
    int gid = blockIdx.x * SCAN_B + tid;
    if (gid < N_NODES) {
        int v = prefix[gid] + blockOff;
        offsets[gid] = v;
        cursors[gid] = v;
    }
}

__global__ __launch_bounds__(256) void scatter_rec_kernel(
    const float* __restrict__ vectors,
    const int* __restrict__ senders,
    const int* __restrict__ receivers,
    const int* __restrict__ species,
    int* __restrict__ cursors,
    float4* __restrict__ feat)
{
    int e = blockIdx.x * blockDim.x + threadIdx.x;
    if (e >= N_EDGES) return;
    int pos = atomicAdd(&cursors[receivers[e]], 1);
    float4 rec;
    rec.x = vectors[3*e+0];
    rec.y = vectors[3*e+1];
    rec.z = vectors[3*e+2];
    rec.w = __int_as_float(species[senders[e]]);
    feat[pos] = rec;
}

// ================= fused node kernel: 64 threads, 1 wave ======
// LDS row per edge: [w0 w4 w1 w5 w2 w6 w3 w7 | Y0..Y15] stride ROW=26
// -> lane (a,m) reads wR pair as one b64 at [2a], Y as b32 at [8+m]
__global__ __launch_bounds__(64) void ace_node_kernel(
    const float4* __restrict__ feat,
    const int* __restrict__ counts,
    const int* __restrict__ offsets,   // null -> bucket mode
    const int* __restrict__ species,
    const float* __restrict__ node_mask,
    const float* __restrict__ wA,
    const float* __restrict__ c_read,
    const float* __restrict__ E0,
    const float* __restrict__ c_pair,
    float* __restrict__ outE,
    float* __restrict__ outB)
{
    int n = blockIdx.x;
    int tid = threadIdx.x;          // tid = a*16 + m, a in [0,4), m in [0,16)
    int a = tid >> 4, m = tid & 15;

    __shared__ float sE[CH * ROW];
    __shared__ float sWA[64];       // wA[8 species][8]
    __shared__ float sCP[64];       // c_pair[zr][8 species][8]
    __shared__ float sA[128];
    __shared__ float sP[32];

    int zr = species[n];
    sWA[tid] = wA[tid];
    sCP[tid] = c_pair[(size_t)zr * 64 + tid];
    int cnt = counts[n];
    size_t start;
    if (offsets) start = (size_t)offsets[n];
    else { cnt = min(cnt, CAP); start = (size_t)n * CAP; }
    __syncthreads();

    float acc0 = 0.0f;     // A[a][m]
    float acc1 = 0.0f;     // A[a+4][m]
    float epAcc = 0.0f;    // pair-energy partial

    for (int base = 0; base < cnt; base += CH) {
        int nE = min(CH, cnt - base);
        if (tid < nE) {
            float4 rec = feat[start + base + tid];
            float vx = rec.x, vy = rec.y, vz = rec.z;
            int zs = __float_as_int(rec.w);
            float r2 = vx*vx + vy*vy + vz*vz + 1e-12f;
            float invr = rsqrtf(r2);
            float r  = r2 * invr;
            float dd = r * 0.2f;                   // r / RCUT
            float d2 = dd*dd, d6 = d2*d2*d2;
            float env = 1.0f + d6 * (-28.0f + 48.0f*dd - 21.0f*d2);  // p=6 envelope
            env = (dd < 1.0f) ? env : 0.0f;
            float pref = 0.6324555320336759f * invr * env;  // sqrt(2/RCUT)*env/r

            float x = 3.14159265358979f * dd;      // in [0, pi]
            float sp = __sinf(x), cp = __cosf(x);  // hw v_sin/v_cos
            float twoc = 2.0f * cp;
            float Rn[NMAX];
            float s_prev = 0.0f, s_cur = sp;
            Rn[0] = pref * s_cur;
            #pragma unroll
            for (int nn = 1; nn < NMAX; ++nn) {
                float s_next = twoc * s_cur - s_prev;
                s_prev = s_cur; s_cur = s_next;
                Rn[nn] = pref * s_cur;
            }

            float ep = 0.0f;
            #pragma unroll
            for (int nn = 0; nn < NMAX; ++nn) ep += sCP[zs*8+nn] * Rn[nn];
            epAcc += 0.5f * ep;

            float* row = &sE[tid * ROW];
            // interleaved wR: [w0 w4 w1 w5 w2 w6 w3 w7]
            #pragma unroll
            for (int aa = 0; aa < 4; ++aa) {
                row[2*aa]   = sWA[zs*8+aa]   * Rn[aa];
                row[2*aa+1] = sWA[zs*8+aa+4] * Rn[aa+4];
            }

            float ux = vx*invr, uy = vy*invr, uz = vz*invr;
            float xx = ux*ux, yy = uy*uy, zz = uz*uz;
            row[8+0]  = 0.28209479177387814f;
            row[8+1]  = 0.4886025119029199f  * uy;
            row[8+2]  = 0.4886025119029199f  * uz;
            row[8+3]  = 0.4886025119029199f  * ux;
            row[8+4]  = 1.0925484305920792f  * ux * uy;
            row[8+5]  = 1.0925484305920792f  * uy * uz;
            row[8+6]  = 0.31539156525252005f * (3.0f*zz - 1.0f);
            row[8+7]  = 1.0925484305920792f  * ux * uz;
            row[8+8]  = 0.5462742152960396f  * (xx - yy);
            row[8+9]  = 0.5900435899266435f  * uy * (3.0f*xx - yy);
            row[8+10] = 2.890611442640554f   * ux * uy * uz;
            row[8+11] = 0.4570457994644658f  * uy * (5.0f*zz - 1.0f);
            row[8+12] = 0.3731763325901154f  * uz * (5.0f*zz - 3.0f);
            row[8+13] = 0.4570457994644658f  * ux * (5.0f*zz - 1.0f);
            row[8+14] = 1.445305721320277f   * uz * (xx - yy);
            row[8+15] = 0.5900435899266435f  * ux * (xx - 3.0f*yy);
        }
        __syncthreads();
        #pragma unroll 4
        for (int e = 0; e < nE; ++e) {
            const float* row = &sE[e * ROW];
            float2 w = *(const float2*)&row[2*a];   // one ds_read_b64
            float  y = row[8+m];                    // one ds_read_b32
            acc0 += w.x * y;
            acc1 += w.y * y;
        }
        __syncthreads();
    }

    sA[tid]      = acc0;    // A[a][m]   (tid == a*16+m)
    sA[tid + 64] = acc1;    // A[a+4][m]
    __syncthreads();

    if (tid < 32) {
        int aa = tid >> 2, l = tid & 3;
        int m0 = l*l, m1 = (l+1)*(l+1);
        float s = 0.0f;
        for (int mm = m0; mm < m1; ++mm) { float v = sA[aa*16+mm]; s += v*v; }
        sP[tid] = s;   // sP[a*4 + l]
    }
    __syncthreads();

    const float* cr = c_read + (size_t)zr * NUM_BASIS;
    float* Brow = outB + (size_t)n * NUM_BASIS;
    float Ep = 0.0f;

    #pragma unroll
    for (int it = 0; it < 15; ++it) {
        int j = tid + it*64;
        if (j < NUM_BASIS) {
            float Bj;
            if (j < 32) {
                Bj = sP[j];
            } else {
                int q = j - 32;            // q = a*112 + l*28 + k*4 + m
                int mm = q & 3;
                int t = q >> 2;            // a*28 + l*7 + k
                int k = t % 7;
                int t2 = t / 7;            // a*4 + l
                int l = t2 & 3;
                int aa = t2 >> 2;
                int o = k + (k >= aa ? 1 : 0);   // _IDX_OTHER[a][k]
                Bj = sP[aa*4 + l] * sP[o*4 + mm];
            }
            Brow[j] = Bj;
            Ep += Bj * cr[j];
        }
    }

    float v = Ep + epAcc;
    #pragma unroll
    for (int off = 32; off > 0; off >>= 1)
        v += __shfl_down(v, off);
    if (tid == 0) outE[n] = (v + E0[zr]) * node_mask[n];
}

extern "C" void kernel_launch(void* const* d_in, const int* in_sizes, int n_in,
                              void* d_out, int out_size, void* d_ws, size_t ws_size,
                              hipStream_t stream) {
    const float* vectors   = (const float*)d_in[0];
    const int*   senders   = (const int*)d_in[1];
    const int*   receivers = (const int*)d_in[2];
    const int*   species   = (const int*)d_in[3];
    const float* node_mask = (const float*)d_in[4];
    const float* wA        = (const float*)d_in[5];
    const float* c_read    = (const float*)d_in[6];
    const float* E0        = (const float*)d_in[7];
    const float* c_pair    = (const float*)d_in[8];

    float* outE = (float*)d_out;        // [20000]
    float* outB = outE + N_NODES;       // [20000][928]

    size_t bucketBytes = (size_t)N_NODES * CAP * sizeof(float4);
    size_t primaryNeed = bucketBytes + N_NODES * sizeof(int);

    if (ws_size >= primaryNeed) {
        // ---- primary: 3 dispatches ----
        float4* feat  = (float4*)d_ws;
        int*   counts = (int*)((char*)d_ws + bucketBytes);
        hipMemsetAsync(counts, 0, N_NODES * sizeof(int), stream);
        bucket_kernel<<<(N_EDGES + 255)/256, 256, 0, stream>>>(
            vectors, senders, receivers, species, feat, counts);
        ace_node_kernel<<<N_NODES, 64, 0, stream>>>(
            feat, counts, (const int*)nullptr, species, node_mask,
            wA, c_read, E0, c_pair, outE, outB);
    } else {
        // ---- fallback: exact CSR of records (10.6 MB) ----
        float4* feat   = (float4*)d_ws;                    // 640000 recs
        int* counts    = (int*)((char*)d_ws + (size_t)N_EDGES * sizeof(float4));
        int* offsets   = counts + N_NODES;
        int* cursors   = offsets + N_NODES;
        int* prefix    = cursors + N_NODES;
        int* blockSums = prefix + N_NODES;
        hipMemsetAsync(counts, 0, N_NODES * sizeof(int), stream);
        count_kernel<<<(N_EDGES + 255)/256, 256, 0, stream>>>(receivers, counts);
        scan_blocks<<<SCAN_NB, SCAN_B, 0, stream>>>(counts, prefix, blockSums);
        scan_finalize<<<SCAN_NB, SCAN_B, 0, stream>>>(prefix, blockSums, offsets, cursors);
        scatter_rec_kernel<<<(N_EDGES + 255)/256, 256, 0, stream>>>(
            vectors, senders, receivers, species, cursors, feat);
        ace_node_kernel<<<N_NODES, 64, 0, stream>>>(
            feat, counts, offsets, species, node_mask,
            wA, c_read, E0, c_pair, outE, outB);
    }
}

// Round 7
// 160.066 us; speedup vs baseline: 1.0766x; 1.0766x over previous
//
#include <hip/hip_runtime.h>
#include <math.h>

#define N_NODES 20000
#define N_EDGES 640000
#define NMAX 8
#define NUM_BASIS 928
#define CH 64             // edge chunk per node-kernel iteration
#define ROW 26            // LDS row stride (dwords)
#define NSLICE 8          // sub-buckets per node (blockIdx&7 ~ XCD heuristic)
#define CAP2 32           // slots per sub-bucket (Poisson(4); P(>32) ~ 1e-20)
#define CAPF 80           // fallback CSR bucket capacity
#define SCAN_B 1024
#define SCAN_NB ((N_NODES + SCAN_B - 1) / SCAN_B)   // 20

// ================= primary path: XCD-sliced single-pass bucket build =================
__global__ __launch_bounds__(256) void bucket_kernel(
    const float* __restrict__ vectors,
    const int* __restrict__ senders,
    const int* __restrict__ receivers,
    const int* __restrict__ species,
    float4* __restrict__ feat,       // [N_NODES][NSLICE][CAP2]
    int* __restrict__ counts)        // [N_NODES][NSLICE]
{
    int e = blockIdx.x * blockDim.x + threadIdx.x;
    if (e >= N_EDGES) return;
    int slice = blockIdx.x & (NSLICE - 1);
    int rcv = receivers[e];
    float4 rec;
    rec.x = vectors[3*e+0];
    rec.y = vectors[3*e+1];
    rec.z = vectors[3*e+2];
    rec.w = __int_as_float(species[senders[e]]);
    int pos = atomicAdd(&counts[rcv * NSLICE + slice], 1);
    if (pos < CAP2) feat[((size_t)rcv * NSLICE + slice) * CAP2 + pos] = rec;
}

// ================= fallback path: exact CSR of records =================
__global__ __launch_bounds__(256) void count_kernel(const int* __restrict__ receivers,
                                                    int* __restrict__ counts) {
    int e = blockIdx.x * blockDim.x + threadIdx.x;
    if (e < N_EDGES) atomicAdd(&counts[receivers[e]], 1);
}

__global__ __launch_bounds__(SCAN_B) void scan_blocks(const int* __restrict__ counts,
                                                      int* __restrict__ prefix,
                                                      int* __restrict__ blockSums) {
    int tid = threadIdx.x;
    int gid = blockIdx.x * SCAN_B + tid;
    int c = (gid < N_NODES) ? counts[gid] : 0;
    int lane = tid & 63, wave = tid >> 6;
    int s = c;
    #pragma unroll
    for (int off = 1; off < 64; off <<= 1) {
        int v = __shfl_up(s, off);
        if (lane >= off) s += v;
    }
    __shared__ int waveTot[16];
    __shared__ int waveExcl[16];
    if (lane == 63) waveTot[wave] = s;
    __syncthreads();
    if (tid == 0) {
        int run = 0;
        #pragma unroll
        for (int w = 0; w < 16; ++w) { waveExcl[w] = run; run += waveTot[w]; }
        blockSums[blockIdx.x] = run;
    }
    __syncthreads();
    int excl = (s - c) + waveExcl[wave];
    if (gid < N_NODES) prefix[gid] = excl;
}

__global__ __launch_bounds__(SCAN_B) void scan_finalize(const int* __restrict__ prefix,
                                                        const int* __restrict__ blockSums,
                                                        int* __restrict__ offsets,
                                                        int* __restrict__ cursors) {
    __shared__ int blockOff;
    int tid = threadIdx.x;
    if (tid == 0) {
        int run = 0;
        for (int b = 0; b < blockIdx.x; ++b) run += blockSums[b];
        blockOff = run;
    }
    __syncthreads();
    int gid = blockIdx.x * SCAN_B + tid;
    if (gid < N_NODES) {
        int v = prefix[gid] + blockOff;
        offsets[gid] = v;
        cursors[gid] = v;
    }
}

__global__ __launch_bounds__(256) void scatter_rec_kernel(
    const float* __restrict__ vectors,
    const int* __restrict__ senders,
    const int* __restrict__ receivers,
    const int* __restrict__ species,
    int* __restrict__ cursors,
    float4* __restrict__ feat)
{
    int e = blockIdx.x * blockDim.x + threadIdx.x;
    if (e >= N_EDGES) return;
    float4 rec;
    rec.x = vectors[3*e+0];
    rec.y = vectors[3*e+1];
    rec.z = vectors[3*e+2];
    rec.w = __int_as_float(species[senders[e]]);
    int pos = atomicAdd(&cursors[receivers[e]], 1);
    feat[pos] = rec;
}

// ===== shared device body: per-edge record -> LDS row (wR interleaved + Y) =====
__device__ __forceinline__ void edge_to_lds(float4 rec, float* row,
                                            const float* sWA, const float* sCP,
                                            float& epAcc)
{
    float vx = rec.x, vy = rec.y, vz = rec.z;
    int zs = __float_as_int(rec.w);
    float r2 = vx*vx + vy*vy + vz*vz + 1e-12f;
    float invr = rsqrtf(r2);
    float r  = r2 * invr;
    float dd = r * 0.2f;                   // r / RCUT
    float d2 = dd*dd, d6 = d2*d2*d2;
    float env = 1.0f + d6 * (-28.0f + 48.0f*dd - 21.0f*d2);  // p=6 envelope
    env = (dd < 1.0f) ? env : 0.0f;
    float pref = 0.6324555320336759f * invr * env;  // sqrt(2/RCUT)*env/r

    float x = 3.14159265358979f * dd;      // in [0, pi]
    float sp = __sinf(x), cp = __cosf(x);
    float twoc = 2.0f * cp;
    float Rn[NMAX];
    float s_prev = 0.0f, s_cur = sp;
    Rn[0] = pref * s_cur;
    #pragma unroll
    for (int nn = 1; nn < NMAX; ++nn) {
        float s_next = twoc * s_cur - s_prev;
        s_prev = s_cur; s_cur = s_next;
        Rn[nn] = pref * s_cur;
    }

    float ep = 0.0f;
    #pragma unroll
    for (int nn = 0; nn < NMAX; ++nn) ep += sCP[zs*8+nn] * Rn[nn];
    epAcc += 0.5f * ep;

    // interleaved wR: [w0 w4 w1 w5 w2 w6 w3 w7]
    #pragma unroll
    for (int aa = 0; aa < 4; ++aa) {
        row[2*aa]   = sWA[zs*8+aa]   * Rn[aa];
        row[2*aa+1] = sWA[zs*8+aa+4] * Rn[aa+4];
    }

    float ux = vx*invr, uy = vy*invr, uz = vz*invr;
    float xx = ux*ux, yy = uy*uy, zz = uz*uz;
    row[8+0]  = 0.28209479177387814f;
    row[8+1]  = 0.4886025119029199f  * uy;
    row[8+2]  = 0.4886025119029199f  * uz;
    row[8+3]  = 0.4886025119029199f  * ux;
    row[8+4]  = 1.0925484305920792f  * ux * uy;
    row[8+5]  = 1.0925484305920792f  * uy * uz;
    row[8+6]  = 0.31539156525252005f * (3.0f*zz - 1.0f);
    row[8+7]  = 1.0925484305920792f  * ux * uz;
    row[8+8]  = 0.5462742152960396f  * (xx - yy);
    row[8+9]  = 0.5900435899266435f  * uy * (3.0f*xx - yy);
    row[8+10] = 2.890611442640554f   * ux * uy * uz;
    row[8+11] = 0.4570457994644658f  * uy * (5.0f*zz - 1.0f);
    row[8+12] = 0.3731763325901154f  * uz * (5.0f*zz - 3.0f);
    row[8+13] = 0.4570457994644658f  * ux * (5.0f*zz - 1.0f);
    row[8+14] = 1.445305721320277f   * uz * (xx - yy);
    row[8+15] = 0.5900435899266435f  * ux * (xx - 3.0f*yy);
}

// ===== shared device epilogue: A (in sA) -> P -> B -> E =====
__device__ __forceinline__ void node_epilogue(int n, int tid, int zr, float epAcc,
                                              float* sA, float* sP,
                                              const float* __restrict__ c_read,
                                              const float* __restrict__ E0,
                                              const float* __restrict__ node_mask,
                                              float* __restrict__ outE,
                                              float* __restrict__ outB)
{
    if (tid < 32) {
        int aa = tid >> 2, l = tid & 3;
        int m0 = l*l, m1 = (l+1)*(l+1);
        float s = 0.0f;
        for (int mm = m0; mm < m1; ++mm) { float v = sA[aa*16+mm]; s += v*v; }
        sP[tid] = s;   // sP[a*4 + l]
    }
    __syncthreads();

    const float* cr = c_read + (size_t)zr * NUM_BASIS;
    float* Brow = outB + (size_t)n * NUM_BASIS;
    float Ep = 0.0f;

    #pragma unroll
    for (int it = 0; it < 15; ++it) {
        int j = tid + it*64;
        if (j < NUM_BASIS) {
            float Bj;
            if (j < 32) {
                Bj = sP[j];
            } else {
                int q = j - 32;            // q = a*112 + l*28 + k*4 + m
                int mm = q & 3;
                int t = q >> 2;            // a*28 + l*7 + k
                int k = t % 7;
                int t2 = t / 7;            // a*4 + l
                int l = t2 & 3;
                int aa = t2 >> 2;
                int o = k + (k >= aa ? 1 : 0);   // _IDX_OTHER[a][k]
                Bj = sP[aa*4 + l] * sP[o*4 + mm];
            }
            Brow[j] = Bj;
            Ep += Bj * cr[j];
        }
    }

    float v = Ep + epAcc;
    #pragma unroll
    for (int off = 32; off > 0; off >>= 1)
        v += __shfl_down(v, off);
    if (tid == 0) outE[n] = (v + E0[zr]) * node_mask[n];
}

// ================= primary node kernel: sliced buckets ======
__global__ __launch_bounds__(64) void ace_node_sliced(
    const float4* __restrict__ feat,    // [N_NODES][NSLICE][CAP2]
    const int* __restrict__ counts,     // [N_NODES][NSLICE]
    const int* __restrict__ species,
    const float* __restrict__ node_mask,
    const float* __restrict__ wA,
    const float* __restrict__ c_read,
    const float* __restrict__ E0,
    const float* __restrict__ c_pair,
    float* __restrict__ outE,
    float* __restrict__ outB)
{
    int n = blockIdx.x;
    int tid = threadIdx.x;          // tid = a*16 + m
    int a = tid >> 4, m = tid & 15;

    __shared__ float sE[CH * ROW];
    __shared__ float sWA[64];
    __shared__ float sCP[64];
    __shared__ float sA[128];
    __shared__ float sP[32];
    __shared__ int   sPre[NSLICE + 1];

    int zr = species[n];
    sWA[tid] = wA[tid];
    sCP[tid] = c_pair[(size_t)zr * 64 + tid];
    if (tid == 0) {
        int run = 0;
        #pragma unroll
        for (int s = 0; s < NSLICE; ++s) {
            sPre[s] = run;
            run += min(counts[n * NSLICE + s], CAP2);
        }
        sPre[NSLICE] = run;
    }
    __syncthreads();

    int cntT = sPre[NSLICE];
    const float4* fbase = feat + (size_t)n * NSLICE * CAP2;

    float acc0 = 0.0f, acc1 = 0.0f, epAcc = 0.0f;

    for (int base = 0; base < cntT; base += CH) {
        int nE = min(CH, cntT - base);
        if (tid < nE) {
            int j = base + tid;
            int s = 0;
            #pragma unroll
            for (int k = 1; k < NSLICE; ++k) s += (j >= sPre[k]);
            int idx = j - sPre[s];
            float4 rec = fbase[s * CAP2 + idx];
            edge_to_lds(rec, &sE[tid * ROW], sWA, sCP, epAcc);
        }
        __syncthreads();
        #pragma unroll 4
        for (int e = 0; e < nE; ++e) {
            const float* row = &sE[e * ROW];
            float2 w = *(const float2*)&row[2*a];
            float  y = row[8+m];
            acc0 += w.x * y;
            acc1 += w.y * y;
        }
        __syncthreads();
    }

    sA[tid]      = acc0;
    sA[tid + 64] = acc1;
    __syncthreads();
    node_epilogue(n, tid, zr, epAcc, sA, sP, c_read, E0, node_mask, outE, outB);
}

// ================= fallback node kernel: contiguous CSR ======
__global__ __launch_bounds__(64) void ace_node_csr(
    const float4* __restrict__ feat,
    const int* __restrict__ counts,
    const int* __restrict__ offsets,
    const int* __restrict__ species,
    const float* __restrict__ node_mask,
    const float* __restrict__ wA,
    const float* __restrict__ c_read,
    const float* __restrict__ E0,
    const float* __restrict__ c_pair,
    float* __restrict__ outE,
    float* __restrict__ outB)
{
    int n = blockIdx.x;
    int tid = threadIdx.x;
    int a = tid >> 4, m = tid & 15;

    __shared__ float sE[CH * ROW];
    __shared__ float sWA[64];
    __shared__ float sCP[64];
    __shared__ float sA[128];
    __shared__ float sP[32];

    int zr = species[n];
    sWA[tid] = wA[tid];
    sCP[tid] = c_pair[(size_t)zr * 64 + tid];
    int cnt = counts[n];
    size_t start = (size_t)offsets[n];
    __syncthreads();

    float acc0 = 0.0f, acc1 = 0.0f, epAcc = 0.0f;

    for (int base = 0; base < cnt; base += CH) {
        int nE = min(CH, cnt - base);
        if (tid < nE) {
            float4 rec = feat[start + base + tid];
            edge_to_lds(rec, &sE[tid * ROW], sWA, sCP, epAcc);
        }
        __syncthreads();
        #pragma unroll 4
        for (int e = 0; e < nE; ++e) {
            const float* row = &sE[e * ROW];
            float2 w = *(const float2*)&row[2*a];
            float  y = row[8+m];
            acc0 += w.x * y;
            acc1 += w.y * y;
        }
        __syncthreads();
    }

    sA[tid]      = acc0;
    sA[tid + 64] = acc1;
    __syncthreads();
    node_epilogue(n, tid, zr, epAcc, sA, sP, c_read, E0, node_mask, outE, outB);
}

extern "C" void kernel_launch(void* const* d_in, const int* in_sizes, int n_in,
                              void* d_out, int out_size, void* d_ws, size_t ws_size,
                              hipStream_t stream) {
    const float* vectors   = (const float*)d_in[0];
    const int*   senders   = (const int*)d_in[1];
    const int*   receivers = (const int*)d_in[2];
    const int*   species   = (const int*)d_in[3];
    const float* node_mask = (const float*)d_in[4];
    const float* wA        = (const float*)d_in[5];
    const float* c_read    = (const float*)d_in[6];
    const float* E0        = (const float*)d_in[7];
    const float* c_pair    = (const float*)d_in[8];

    float* outE = (float*)d_out;        // [20000]
    float* outB = outE + N_NODES;       // [20000][928]

    size_t bucketBytes = (size_t)N_NODES * NSLICE * CAP2 * sizeof(float4);   // 81.9 MB
    size_t countBytes  = (size_t)N_NODES * NSLICE * sizeof(int);             // 640 KB
    size_t primaryNeed = bucketBytes + countBytes;

    if (ws_size >= primaryNeed) {
        // ---- primary: 3 dispatches, XCD-sliced buckets ----
        float4* feat  = (float4*)d_ws;
        int*   counts = (int*)((char*)d_ws + bucketBytes);
        hipMemsetAsync(counts, 0, countBytes, stream);
        bucket_kernel<<<(N_EDGES + 255)/256, 256, 0, stream>>>(
            vectors, senders, receivers, species, feat, counts);
        ace_node_sliced<<<N_NODES, 64, 0, stream>>>(
            feat, counts, species, node_mask,
            wA, c_read, E0, c_pair, outE, outB);
    } else {
        // ---- fallback: exact CSR of records (10.6 MB) ----
        float4* feat   = (float4*)d_ws;                    // 640000 recs
        int* counts    = (int*)((char*)d_ws + (size_t)N_EDGES * sizeof(float4));
        int* offsets   = counts + N_NODES;
        int* cursors   = offsets + N_NODES;
        int* prefix    = cursors + N_NODES;
        int* blockSums = prefix + N_NODES;
        hipMemsetAsync(counts, 0, N_NODES * sizeof(int), stream);
        count_kernel<<<(N_EDGES + 255)/256, 256, 0, stream>>>(receivers, counts);
        scan_blocks<<<SCAN_NB, SCAN_B, 0, stream>>>(counts, prefix, blockSums);
        scan_finalize<<<SCAN_NB, SCAN_B, 0, stream>>>(prefix, blockSums, offsets, cursors);
        scatter_rec_kernel<<<(N_EDGES + 255)/256, 256, 0, stream>>>(
            vectors, senders, receivers, species, cursors, feat);
        ace_node_csr<<<N_NODES, 64, 0, stream>>>(
            feat, counts, offsets, species, node_mask,
            wA, c_read, E0, c_pair, outE, outB);
    }
}

// Round 8
// 147.801 us; speedup vs baseline: 1.1659x; 1.0830x over previous
//
#include <hip/hip_runtime.h>
#include <math.h>

#define N_NODES 20000
#define N_EDGES 640000
#define NMAX 8
#define NUM_BASIS 928
#define CH 64             // edge chunk per node-kernel iteration
#define TR 72             // f16 LDS row stride (k-dim), 144 B -> bank-spread, 16B-aligned
#define NSLICE 8          // sub-buckets per node
#define CAP2 32           // slots per sub-bucket
#define SCAN_B 1024
#define SCAN_NB ((N_NODES + SCAN_B - 1) / SCAN_B)   // 20

typedef _Float16 half8 __attribute__((ext_vector_type(8)));
typedef float floatx4 __attribute__((ext_vector_type(4)));

// ================= primary path: XCD-sliced single-pass bucket build =================
__global__ __launch_bounds__(256) void bucket_kernel(
    const float* __restrict__ vectors,
    const int* __restrict__ senders,
    const int* __restrict__ receivers,
    const int* __restrict__ species,
    float4* __restrict__ feat,       // [N_NODES][NSLICE][CAP2]
    int* __restrict__ counts)        // [N_NODES][NSLICE]
{
    int e = blockIdx.x * blockDim.x + threadIdx.x;
    if (e >= N_EDGES) return;
    int slice = blockIdx.x & (NSLICE - 1);
    int rcv = receivers[e];
    float4 rec;
    rec.x = vectors[3*e+0];
    rec.y = vectors[3*e+1];
    rec.z = vectors[3*e+2];
    rec.w = __int_as_float(species[senders[e]]);
    int pos = atomicAdd(&counts[rcv * NSLICE + slice], 1);
    if (pos < CAP2) feat[((size_t)rcv * NSLICE + slice) * CAP2 + pos] = rec;
}

// ================= fallback path: exact CSR of records =================
__global__ __launch_bounds__(256) void count_kernel(const int* __restrict__ receivers,
                                                    int* __restrict__ counts) {
    int e = blockIdx.x * blockDim.x + threadIdx.x;
    if (e < N_EDGES) atomicAdd(&counts[receivers[e]], 1);
}

__global__ __launch_bounds__(SCAN_B) void scan_blocks(const int* __restrict__ counts,
                                                      int* __restrict__ prefix,
                                                      int* __restrict__ blockSums) {
    int tid = threadIdx.x;
    int gid = blockIdx.x * SCAN_B + tid;
    int c = (gid < N_NODES) ? counts[gid] : 0;
    int lane = tid & 63, wave = tid >> 6;
    int s = c;
    #pragma unroll
    for (int off = 1; off < 64; off <<= 1) {
        int v = __shfl_up(s, off);
        if (lane >= off) s += v;
    }
    __shared__ int waveTot[16];
    __shared__ int waveExcl[16];
    if (lane == 63) waveTot[wave] = s;
    __syncthreads();
    if (tid == 0) {
        int run = 0;
        #pragma unroll
        for (int w = 0; w < 16; ++w) { waveExcl[w] = run; run += waveTot[w]; }
        blockSums[blockIdx.x] = run;
    }
    __syncthreads();
    int excl = (s - c) + waveExcl[wave];
    if (gid < N_NODES) prefix[gid] = excl;
}

__global__ __launch_bounds__(SCAN_B) void scan_finalize(const int* __restrict__ prefix,
                                                        const int* __restrict__ blockSums,
                                                        int* __restrict__ offsets,
                                                        int* __restrict__ cursors) {
    __shared__ int blockOff;
    int tid = threadIdx.x;
    if (tid == 0) {
        int run = 0;
        for (int b = 0; b < blockIdx.x; ++b) run += blockSums[b];
        blockOff = run;
    }
    __syncthreads();
    int gid = blockIdx.x * SCAN_B + tid;
    if (gid < N_NODES) {
        int v = prefix[gid] + blockOff;
        offsets[gid] = v;
        cursors[gid] = v;
    }
}

__global__ __launch_bounds__(256) void scatter_rec_kernel(
    const float* __restrict__ vectors,
    const int* __restrict__ senders,
    const int* __restrict__ receivers,
    const int* __restrict__ species,
    int* __restrict__ cursors,
    float4* __restrict__ feat)
{
    int e = blockIdx.x * blockDim.x + threadIdx.x;
    if (e >= N_EDGES) return;
    float4 rec;
    rec.x = vectors[3*e+0];
    rec.y = vectors[3*e+1];
    rec.z = vectors[3*e+2];
    rec.w = __int_as_float(species[senders[e]]);
    int pos = atomicAdd(&cursors[receivers[e]], 1);
    feat[pos] = rec;
}

// ===== per-edge compute: record -> wR[8], Y[16], epAcc (all f32) =====
__device__ __forceinline__ void edge_compute(float4 rec,
                                             const float* sWA, const float* sCP,
                                             float* wr, float* Yv, float& epAcc)
{
    float vx = rec.x, vy = rec.y, vz = rec.z;
    int zs = __float_as_int(rec.w);
    float r2 = vx*vx + vy*vy + vz*vz + 1e-12f;
    float invr = rsqrtf(r2);
    float r  = r2 * invr;
    float dd = r * 0.2f;                   // r / RCUT
    float d2 = dd*dd, d6 = d2*d2*d2;
    float env = 1.0f + d6 * (-28.0f + 48.0f*dd - 21.0f*d2);  // p=6 envelope
    env = (dd < 1.0f) ? env : 0.0f;
    float pref = 0.6324555320336759f * invr * env;  // sqrt(2/RCUT)*env/r

    float x = 3.14159265358979f * dd;      // in [0, pi]
    float sp = __sinf(x), cp = __cosf(x);
    float twoc = 2.0f * cp;
    float Rn[NMAX];
    float s_prev = 0.0f, s_cur = sp;
    Rn[0] = pref * s_cur;
    #pragma unroll
    for (int nn = 1; nn < NMAX; ++nn) {
        float s_next = twoc * s_cur - s_prev;
        s_prev = s_cur; s_cur = s_next;
        Rn[nn] = pref * s_cur;
    }

    float ep = 0.0f;
    #pragma unroll
    for (int nn = 0; nn < NMAX; ++nn) ep += sCP[zs*8+nn] * Rn[nn];
    epAcc += 0.5f * ep;

    #pragma unroll
    for (int nn = 0; nn < NMAX; ++nn) wr[nn] = sWA[zs*8+nn] * Rn[nn];

    float ux = vx*invr, uy = vy*invr, uz = vz*invr;
    float xx = ux*ux, yy = uy*uy, zz = uz*uz;
    Yv[0]  = 0.28209479177387814f;
    Yv[1]  = 0.4886025119029199f  * uy;
    Yv[2]  = 0.4886025119029199f  * uz;
    Yv[3]  = 0.4886025119029199f  * ux;
    Yv[4]  = 1.0925484305920792f  * ux * uy;
    Yv[5]  = 1.0925484305920792f  * uy * uz;
    Yv[6]  = 0.31539156525252005f * (3.0f*zz - 1.0f);
    Yv[7]  = 1.0925484305920792f  * ux * uz;
    Yv[8]  = 0.5462742152960396f  * (xx - yy);
    Yv[9]  = 0.5900435899266435f  * uy * (3.0f*xx - yy);
    Yv[10] = 2.890611442640554f   * ux * uy * uz;
    Yv[11] = 0.4570457994644658f  * uy * (5.0f*zz - 1.0f);
    Yv[12] = 0.3731763325901154f  * uz * (5.0f*zz - 3.0f);
    Yv[13] = 0.4570457994644658f  * ux * (5.0f*zz - 1.0f);
    Yv[14] = 1.445305721320277f   * uz * (xx - yy);
    Yv[15] = 0.5900435899266435f  * ux * (xx - 3.0f*yy);
}

// ===== epilogue: A (in sA) -> P -> B -> E =====
__device__ __forceinline__ void node_epilogue(int n, int tid, int zr, float epAcc,
                                              float* sA, float* sP,
                                              const float* __restrict__ c_read,
                                              const float* __restrict__ E0,
                                              const float* __restrict__ node_mask,
                                              float* __restrict__ outE,
                                              float* __restrict__ outB)
{
    if (tid < 32) {
        int aa = tid >> 2, l = tid & 3;
        int m0 = l*l, m1 = (l+1)*(l+1);
        float s = 0.0f;
        for (int mm = m0; mm < m1; ++mm) { float v = sA[aa*16+mm]; s += v*v; }
        sP[tid] = s;   // sP[a*4 + l]
    }
    __syncthreads();

    const float* cr = c_read + (size_t)zr * NUM_BASIS;
    float* Brow = outB + (size_t)n * NUM_BASIS;
    float Ep = 0.0f;

    #pragma unroll
    for (int it = 0; it < 15; ++it) {
        int j = tid + it*64;
        if (j < NUM_BASIS) {
            float Bj;
            if (j < 32) {
                Bj = sP[j];
            } else {
                int q = j - 32;            // q = a*112 + l*28 + k*4 + m
                int mm = q & 3;
                int t = q >> 2;            // a*28 + l*7 + k
                int k = t % 7;
                int t2 = t / 7;            // a*4 + l
                int l = t2 & 3;
                int aa = t2 >> 2;
                int o = k + (k >= aa ? 1 : 0);   // _IDX_OTHER[a][k]
                Bj = sP[aa*4 + l] * sP[o*4 + mm];
            }
            Brow[j] = Bj;
            Ep += Bj * cr[j];
        }
    }

    float v = Ep + epAcc;
    #pragma unroll
    for (int off = 32; off > 0; off >>= 1)
        v += __shfl_down(v, off);
    if (tid == 0) outE[n] = (v + E0[zr]) * node_mask[n];
}

// ================= MFMA node kernel (templated on gather mode) ======
// A[a][m] = sum_e wR[e][a]*Y[e][m]  ==  D(16x16) = wRT(16xK) * YT^T(Kx16) via
// v_mfma_f32_16x16x32_f16; K = edge chunks of 32. Rows a=8..15 of A are pad.
template<bool SLICED>
__global__ __launch_bounds__(64) void ace_node_kernel(
    const float4* __restrict__ feat,
    const int* __restrict__ counts,     // SLICED: [N][NSLICE]; else [N]
    const int* __restrict__ offsets,    // CSR only
    const int* __restrict__ species,
    const float* __restrict__ node_mask,
    const float* __restrict__ wA,
    const float* __restrict__ c_read,
    const float* __restrict__ E0,
    const float* __restrict__ c_pair,
    float* __restrict__ outE,
    float* __restrict__ outB)
{
    int n = blockIdx.x;
    int tid = threadIdx.x;
    int row = tid & 15, quad = tid >> 4;

    __shared__ __align__(16) _Float16 sWRT[16 * TR];  // [a][e] f16
    __shared__ __align__(16) _Float16 sYT [16 * TR];  // [m][e] f16
    __shared__ float sWA[64];
    __shared__ float sCP[64];
    __shared__ float sA[128];
    __shared__ float sP[32];
    __shared__ int   sPre[NSLICE + 1];

    int zr = species[n];
    sWA[tid] = wA[tid];
    sCP[tid] = c_pair[(size_t)zr * 64 + tid];

    int cntT;
    size_t start = 0;
    if (SLICED) {
        if (tid == 0) {
            int run = 0;
            #pragma unroll
            for (int s = 0; s < NSLICE; ++s) {
                sPre[s] = run;
                run += min(counts[n * NSLICE + s], CAP2);
            }
            sPre[NSLICE] = run;
        }
    } else {
        start = (size_t)offsets[n];
    }

    // zero the A-operand pad rows (8..15) once: 8*TR f16 = 288 dwords
    for (int i = tid; i < (8 * TR) / 2; i += 64)
        ((unsigned int*)&sWRT[8 * TR])[i] = 0u;

    __syncthreads();
    cntT = SLICED ? sPre[NSLICE] : counts[n];
    const float4* fbase = SLICED ? feat + (size_t)n * NSLICE * CAP2 : feat + start;

    floatx4 acc = {0.0f, 0.0f, 0.0f, 0.0f};
    float epAcc = 0.0f;

    for (int base = 0; base < cntT; base += CH) {
        int nE = min(CH, cntT - base);
        float wr[8] = {0,0,0,0,0,0,0,0};
        float Yv[16] = {0,0,0,0,0,0,0,0,0,0,0,0,0,0,0,0};
        if (tid < nE) {
            int j = base + tid;
            float4 rec;
            if (SLICED) {
                int s = 0;
                #pragma unroll
                for (int k = 1; k < NSLICE; ++k) s += (j >= sPre[k]);
                rec = fbase[s * CAP2 + (j - sPre[s])];
            } else {
                rec = fbase[j];
            }
            edge_compute(rec, sWA, sCP, wr, Yv, epAcc);
        }
        // transpose to k-contiguous f16 operand layout (zeros for e >= nE)
        #pragma unroll
        for (int aa = 0; aa < 8; ++aa)  sWRT[aa * TR + tid] = (_Float16)wr[aa];
        #pragma unroll
        for (int mm = 0; mm < 16; ++mm) sYT [mm * TR + tid] = (_Float16)Yv[mm];
        __syncthreads();

        acc = __builtin_amdgcn_mfma_f32_16x16x32_f16(
            *(const half8*)&sWRT[row * TR + quad * 8],
            *(const half8*)&sYT [row * TR + quad * 8], acc, 0, 0, 0);
        if (nE > 32)
            acc = __builtin_amdgcn_mfma_f32_16x16x32_f16(
                *(const half8*)&sWRT[row * TR + 32 + quad * 8],
                *(const half8*)&sYT [row * TR + 32 + quad * 8], acc, 0, 0, 0);
        __syncthreads();
    }

    // D[i=quad*4+reg][j=row]; rows 0..7 hold A[a][m]
    if (quad < 2) {
        #pragma unroll
        for (int rg = 0; rg < 4; ++rg)
            sA[(quad * 4 + rg) * 16 + row] = acc[rg];
    }
    __syncthreads();

    node_epilogue(n, tid, zr, epAcc, sA, sP, c_read, E0, node_mask, outE, outB);
}

extern "C" void kernel_launch(void* const* d_in, const int* in_sizes, int n_in,
                              void* d_out, int out_size, void* d_ws, size_t ws_size,
                              hipStream_t stream) {
    const float* vectors   = (const float*)d_in[0];
    const int*   senders   = (const int*)d_in[1];
    const int*   receivers = (const int*)d_in[2];
    const int*   species   = (const int*)d_in[3];
    const float* node_mask = (const float*)d_in[4];
    const float* wA        = (const float*)d_in[5];
    const float* c_read    = (const float*)d_in[6];
    const float* E0        = (const float*)d_in[7];
    const float* c_pair    = (const float*)d_in[8];

    float* outE = (float*)d_out;        // [20000]
    float* outB = outE + N_NODES;       // [20000][928]

    size_t bucketBytes = (size_t)N_NODES * NSLICE * CAP2 * sizeof(float4);   // 81.9 MB
    size_t countBytes  = (size_t)N_NODES * NSLICE * sizeof(int);             // 640 KB
    size_t primaryNeed = bucketBytes + countBytes;

    if (ws_size >= primaryNeed) {
        // ---- primary: 3 dispatches, XCD-sliced buckets ----
        float4* feat  = (float4*)d_ws;
        int*   counts = (int*)((char*)d_ws + bucketBytes);
        hipMemsetAsync(counts, 0, countBytes, stream);
        bucket_kernel<<<(N_EDGES + 255)/256, 256, 0, stream>>>(
            vectors, senders, receivers, species, feat, counts);
        ace_node_kernel<true><<<N_NODES, 64, 0, stream>>>(
            feat, counts, (const int*)nullptr, species, node_mask,
            wA, c_read, E0, c_pair, outE, outB);
    } else {
        // ---- fallback: exact CSR of records (10.6 MB) ----
        float4* feat   = (float4*)d_ws;                    // 640000 recs
        int* counts    = (int*)((char*)d_ws + (size_t)N_EDGES * sizeof(float4));
        int* offsets   = counts + N_NODES;
        int* cursors   = offsets + N_NODES;
        int* prefix    = cursors + N_NODES;
        int* blockSums = prefix + N_NODES;
        hipMemsetAsync(counts, 0, N_NODES * sizeof(int), stream);
        count_kernel<<<(N_EDGES + 255)/256, 256, 0, stream>>>(receivers, counts);
        scan_blocks<<<SCAN_NB, SCAN_B, 0, stream>>>(counts, prefix, blockSums);
        scan_finalize<<<SCAN_NB, SCAN_B, 0, stream>>>(prefix, blockSums, offsets, cursors);
        scatter_rec_kernel<<<(N_EDGES + 255)/256, 256, 0, stream>>>(
            vectors, senders, receivers, species, cursors, feat);
        ace_node_kernel<false><<<N_NODES, 64, 0, stream>>>(
            feat, counts, offsets, species, node_mask,
            wA, c_read, E0, c_pair, outE, outB);
    }
}